// Round 1
// baseline (934.292 us; speedup 1.0000x reference)
//
#include <hip/hip_runtime.h>
#include <stdint.h>

// ---------------------------------------------------------------------------
// BatchWhiten: out = x @ inv_sqrtm(max(0.1*running + 0.9*(x^T x)/N, 1e-5))
// x: [262144, 512] fp32, running: [512,512] fp32, out: [262144,512] fp32
// ---------------------------------------------------------------------------

#define N_ROWS 262144
#define D 512
#define NS_ITERS 7
#define CK_CHUNKS 64
#define CK_ROWS (N_ROWS / CK_CHUNKS)  // 4096
#define CK_STEPS (CK_ROWS / 32)       // 128

typedef float f32x4 __attribute__((ext_vector_type(4)));
typedef short s16x8 __attribute__((ext_vector_type(8)));
typedef short s16x4 __attribute__((ext_vector_type(4)));
typedef __bf16 bf16x8 __attribute__((ext_vector_type(8)));

static __device__ __forceinline__ unsigned short f2bf(float f) {
  unsigned u = __float_as_uint(f);
  u += 0x7FFFu + ((u >> 16) & 1u);  // RNE
  return (unsigned short)(u >> 16);
}

static __device__ __forceinline__ f32x4 mfma16(s16x8 a, s16x8 b, f32x4 c) {
  return __builtin_amdgcn_mfma_f32_16x16x32_bf16(
      __builtin_bit_cast(bf16x8, a), __builtin_bit_cast(bf16x8, b), c, 0, 0, 0);
}

#define SWZ4(c) (((c) ^ ((c) >> 2)) & 3)
#define SWZ8(c) (((c) ^ ((c) >> 3)) & 7)

// ---------------------------------------------------------------------------
// Kernel 1: C += x^T x, split-K, bf16 MFMA, upper tiles (mb<=nb) only.
// grid (10, CK_CHUNKS), block 256. LDS tile layout: lds[c][k], row = 32
// shorts (64B), 4 chunks of 8 bf16 swizzled by SWZ4(c).
// ---------------------------------------------------------------------------
__global__ __launch_bounds__(256) void covar_k(const float* __restrict__ x,
                                               float* __restrict__ C) {
  __shared__ short ldsA[128 * 32];
  __shared__ short ldsB[128 * 32];

  int t = blockIdx.x, mb = 0, rl = 4;
  while (t >= rl) { t -= rl; ++mb; --rl; }
  const int nb = mb + t;

  const int tid = threadIdx.x;
  const int c2 = (tid & 63) * 2;  // 0,2,..,126
  const int kh = tid >> 6;        // 0..3 (k-chunk of 8)

  const int lane = tid & 63;
  const int wave = tid >> 6;
  const int wr = wave >> 1, wc = wave & 1;
  const int l15 = lane & 15, g = lane >> 4;

  f32x4 acc[4][4];
#pragma unroll
  for (int i = 0; i < 4; ++i)
#pragma unroll
    for (int j = 0; j < 4; ++j) acc[i][j] = f32x4{0.f, 0.f, 0.f, 0.f};

  const size_t kbase0 = (size_t)blockIdx.y * CK_ROWS;

  for (int st = 0; st < CK_STEPS; ++st) {
    const size_t k0 = kbase0 + (size_t)st * 32;
    __syncthreads();
    {  // stage M-block
      const float* src = x + (k0 + kh * 8) * D + mb * 128 + c2;
      s16x8 p0, p1;
#pragma unroll
      for (int q = 0; q < 8; ++q) {
        float2 v = *(const float2*)(src + (size_t)q * D);
        p0[q] = (short)f2bf(v.x);
        p1[q] = (short)f2bf(v.y);
      }
      *(s16x8*)(ldsA + c2 * 32 + ((kh ^ SWZ4(c2)) << 3)) = p0;
      *(s16x8*)(ldsA + (c2 + 1) * 32 + ((kh ^ SWZ4(c2 + 1)) << 3)) = p1;
    }
    if (nb != mb) {  // stage N-block
      const float* src = x + (k0 + kh * 8) * D + nb * 128 + c2;
      s16x8 p0, p1;
#pragma unroll
      for (int q = 0; q < 8; ++q) {
        float2 v = *(const float2*)(src + (size_t)q * D);
        p0[q] = (short)f2bf(v.x);
        p1[q] = (short)f2bf(v.y);
      }
      *(s16x8*)(ldsB + c2 * 32 + ((kh ^ SWZ4(c2)) << 3)) = p0;
      *(s16x8*)(ldsB + (c2 + 1) * 32 + ((kh ^ SWZ4(c2 + 1)) << 3)) = p1;
    }
    __syncthreads();

    const short* Bp = (nb != mb) ? ldsB : ldsA;
    s16x8 af[4], bfv[4];
#pragma unroll
    for (int mi = 0; mi < 4; ++mi) {
      int m = 64 * wr + 16 * mi + l15;
      af[mi] = *(const s16x8*)(ldsA + m * 32 + ((g ^ SWZ4(m)) << 3));
    }
#pragma unroll
    for (int nj = 0; nj < 4; ++nj) {
      int n = 64 * wc + 16 * nj + l15;
      bfv[nj] = *(const s16x8*)(Bp + n * 32 + ((g ^ SWZ4(n)) << 3));
    }
#pragma unroll
    for (int mi = 0; mi < 4; ++mi)
#pragma unroll
      for (int nj = 0; nj < 4; ++nj)
        acc[mi][nj] = mfma16(af[mi], bfv[nj], acc[mi][nj]);
  }

  // epilogue: atomic accumulate into upper tile (mb,nb)
#pragma unroll
  for (int mi = 0; mi < 4; ++mi)
#pragma unroll
    for (int nj = 0; nj < 4; ++nj) {
      const int n = nb * 128 + 64 * wc + 16 * nj + l15;
#pragma unroll
      for (int r = 0; r < 4; ++r) {
        const int m = mb * 128 + 64 * wr + 16 * mi + 4 * g + r;
        atomicAdd(&C[(size_t)m * D + n], acc[mi][nj][r]);
      }
    }
}

// ---------------------------------------------------------------------------
// Kernel 2: M = max(0.1*running + (0.9/N)*C_sym, 1e-5); sMax = max row sum.
// grid 512 (one row per block), block 256.
// ---------------------------------------------------------------------------
__global__ __launch_bounds__(256) void prep_k(const float* __restrict__ C,
                                              const float* __restrict__ run,
                                              float* __restrict__ M,
                                              unsigned* __restrict__ sMax) {
  const int r = blockIdx.x;
  const int t = threadIdx.x;
  const float cs = 0.9f / (float)N_ROWS;
  float sum = 0.f;
  for (int c = t; c < D; c += 256) {
    const int rr = r < c ? r : c;
    const int cc = r < c ? c : r;
    float v = 0.1f * run[(size_t)r * D + c] + cs * C[(size_t)rr * D + cc];
    v = fmaxf(v, 1e-5f);
    M[(size_t)r * D + c] = v;
    sum += v;  // all entries positive after clamp
  }
  __shared__ float red[256];
  red[t] = sum;
  __syncthreads();
  for (int off = 128; off > 0; off >>= 1) {
    if (t < off) red[t] += red[t + off];
    __syncthreads();
  }
  if (t == 0) atomicMax(sMax, __float_as_uint(red[0]));
}

// ---------------------------------------------------------------------------
// Kernel 3: Y = M/s ; Z = I.   grid 1024, block 256.
// ---------------------------------------------------------------------------
__global__ __launch_bounds__(256) void inityz_k(const float* __restrict__ M,
                                                const unsigned* __restrict__ sMax,
                                                float* __restrict__ Y,
                                                float* __restrict__ Z) {
  const float inv = 1.0f / __uint_as_float(*sMax);
  const int i = blockIdx.x * 256 + threadIdx.x;
  Y[i] = M[i] * inv;
  Z[i] = ((i >> 9) == (i & 511)) ? 1.0f : 0.0f;
}

// ---------------------------------------------------------------------------
// 512x512x512 fp32 matmul body (32x32 tile / block, 2x2 per thread)
// ---------------------------------------------------------------------------
__device__ __forceinline__ void mm512_body(const float* __restrict__ A,
                                           const float* __restrict__ B,
                                           float* a00, float* a01, float* a10,
                                           float* a11, int rbase, int cbase) {
  __shared__ float As[32][36];
  __shared__ float Bs[32][36];
  const int t = threadIdx.x;
  const int tx = t & 15, ty = t >> 4;
  const int sr = t >> 3, sc = (t & 7) * 4;
  float c00 = 0.f, c01 = 0.f, c10 = 0.f, c11 = 0.f;
  for (int k0 = 0; k0 < D; k0 += 32) {
    __syncthreads();
    *(float4*)&As[sr][sc] = *(const float4*)(A + (size_t)(rbase + sr) * D + k0 + sc);
    *(float4*)&Bs[sr][sc] = *(const float4*)(B + (size_t)(k0 + sr) * D + cbase + sc);
    __syncthreads();
#pragma unroll
    for (int kk = 0; kk < 32; ++kk) {
      const float av0 = As[2 * ty][kk], av1 = As[2 * ty + 1][kk];
      const float2 bv = *(const float2*)&Bs[kk][2 * tx];
      c00 = fmaf(av0, bv.x, c00);
      c01 = fmaf(av0, bv.y, c01);
      c10 = fmaf(av1, bv.x, c10);
      c11 = fmaf(av1, bv.y, c11);
    }
  }
  *a00 = c00; *a01 = c01; *a10 = c10; *a11 = c11;
}

// T = 1.5 I - 0.5 * (Z @ Y)
__global__ __launch_bounds__(256) void mmT_k(const float* __restrict__ Zm,
                                             const float* __restrict__ Ym,
                                             float* __restrict__ T) {
  const int rbase = blockIdx.y * 32, cbase = blockIdx.x * 32;
  float a00, a01, a10, a11;
  mm512_body(Zm, Ym, &a00, &a01, &a10, &a11, rbase, cbase);
  const int tx = threadIdx.x & 15, ty = threadIdx.x >> 4;
  const int r0 = rbase + 2 * ty, c0 = cbase + 2 * tx;
  T[(size_t)r0 * D + c0] = (r0 == c0 ? 1.5f : 0.f) - 0.5f * a00;
  T[(size_t)r0 * D + c0 + 1] = (r0 == c0 + 1 ? 1.5f : 0.f) - 0.5f * a01;
  T[(size_t)(r0 + 1) * D + c0] = (r0 + 1 == c0 ? 1.5f : 0.f) - 0.5f * a10;
  T[(size_t)(r0 + 1) * D + c0 + 1] = (r0 + 1 == c0 + 1 ? 1.5f : 0.f) - 0.5f * a11;
}

// z=0: Ynew = Y @ T ; z=1: Znew = T @ Z
__global__ __launch_bounds__(256) void mmpair_k(const float* __restrict__ Y,
                                                const float* __restrict__ Z,
                                                const float* __restrict__ T,
                                                float* __restrict__ Yn,
                                                float* __restrict__ Zn) {
  const float* A = blockIdx.z ? T : Y;
  const float* B = blockIdx.z ? Z : T;
  float* O = blockIdx.z ? Zn : Yn;
  const int rbase = blockIdx.y * 32, cbase = blockIdx.x * 32;
  float a00, a01, a10, a11;
  mm512_body(A, B, &a00, &a01, &a10, &a11, rbase, cbase);
  const int tx = threadIdx.x & 15, ty = threadIdx.x >> 4;
  const int r0 = rbase + 2 * ty, c0 = cbase + 2 * tx;
  O[(size_t)r0 * D + c0] = a00;
  O[(size_t)r0 * D + c0 + 1] = a01;
  O[(size_t)(r0 + 1) * D + c0] = a10;
  O[(size_t)(r0 + 1) * D + c0 + 1] = a11;
}

// ---------------------------------------------------------------------------
// Kernel 4: build pre-swizzled bf16 B-panels: B = Z / sqrt(s).
// panel layout: [nb(4)][ks(8)][nl(128)][ch'(8)][e(8)] bf16  (512 KB)
// ---------------------------------------------------------------------------
__global__ __launch_bounds__(256) void panel_k(const float* __restrict__ Z,
                                               const unsigned* __restrict__ sMax,
                                               short* __restrict__ panels) {
  const float rs = rsqrtf(__uint_as_float(*sMax));
  const int i = blockIdx.x * 256 + threadIdx.x;  // 0..262143
  const int k = i >> 9, n = i & 511;
  const float v = Z[(size_t)k * D + n] * rs;
  const int nb = n >> 7, nl = n & 127;
  const int ks = k >> 6, kl = k & 63;
  const int ch = (kl >> 3) ^ SWZ8(nl), e = kl & 7;
  const size_t pi = (size_t)(((nb * 8 + ks) * 128 + nl)) * 64 + ch * 8 + e;
  panels[pi] = (short)f2bf(v);
}

// ---------------------------------------------------------------------------
// Kernel 5: out = x @ B.  grid (4, 2048), block 256. 128x128 tile, BK=64.
// LDS rows = 64 shorts (128B), 8 chunks of 8 bf16, swizzled by SWZ8(row).
// ---------------------------------------------------------------------------
__global__ __launch_bounds__(256) void gemm_k(const float* __restrict__ x,
                                              const short* __restrict__ panels,
                                              float* __restrict__ out) {
  __shared__ short ldsA[128 * 64];
  __shared__ short ldsB[128 * 64];
  const int ct = blockIdx.x;
  const size_t rbase = (size_t)blockIdx.y * 128;
  const int tid = threadIdx.x;
  const int lane = tid & 63, wave = tid >> 6;
  const int wr = wave >> 1, wc = wave & 1;
  const int l15 = lane & 15, g = lane >> 4;

  f32x4 acc[4][4];
#pragma unroll
  for (int i = 0; i < 4; ++i)
#pragma unroll
    for (int j = 0; j < 4; ++j) acc[i][j] = f32x4{0.f, 0.f, 0.f, 0.f};

  const int mb8 = tid >> 4;         // 0..15
  const int koff = (tid & 15) * 4;  // 0..60
  const int chA = koff >> 3, subA = koff & 7;

  for (int ks = 0; ks < 8; ++ks) {
    __syncthreads();
    // stage A: x[rbase..rbase+127][ks*64..+63] -> bf16 LDS
#pragma unroll
    for (int i = 0; i < 8; ++i) {
      const int m = mb8 + (i << 4);
      const float4 v = *(const float4*)(x + (rbase + m) * D + ks * 64 + koff);
      s16x4 p;
      p[0] = (short)f2bf(v.x);
      p[1] = (short)f2bf(v.y);
      p[2] = (short)f2bf(v.z);
      p[3] = (short)f2bf(v.w);
      *(s16x4*)(ldsA + m * 64 + ((chA ^ SWZ8(m)) << 3) + subA) = p;
    }
    // stage B: linear copy of pre-swizzled panel slice (16 KB)
    {
      const short* src = panels + ((size_t)(ct * 8 + ks) << 13) + tid * 8;
#pragma unroll
      for (int i = 0; i < 4; ++i)
        *(uint4*)(ldsB + i * 2048 + tid * 8) = *(const uint4*)(src + i * 2048);
    }
    __syncthreads();

#pragma unroll
    for (int kk = 0; kk < 2; ++kk) {
      s16x8 af[4], bfv[4];
#pragma unroll
      for (int mi = 0; mi < 4; ++mi) {
        const int m = 64 * wr + 16 * mi + l15;
        af[mi] = *(const s16x8*)(ldsA + m * 64 + ((((kk << 2) | g) ^ SWZ8(m)) << 3));
      }
#pragma unroll
      for (int nj = 0; nj < 4; ++nj) {
        const int n = 64 * wc + 16 * nj + l15;
        bfv[nj] = *(const s16x8*)(ldsB + n * 64 + ((((kk << 2) | g) ^ SWZ8(n)) << 3));
      }
#pragma unroll
      for (int mi = 0; mi < 4; ++mi)
#pragma unroll
        for (int nj = 0; nj < 4; ++nj)
          acc[mi][nj] = mfma16(af[mi], bfv[nj], acc[mi][nj]);
    }
  }

  // epilogue
#pragma unroll
  for (int mi = 0; mi < 4; ++mi)
#pragma unroll
    for (int nj = 0; nj < 4; ++nj) {
      const size_t row0 = rbase + 64 * wr + 16 * mi + 4 * g;
      const int col = ct * 128 + 64 * wc + 16 * nj + l15;
#pragma unroll
      for (int r = 0; r < 4; ++r)
        out[(row0 + r) * D + col] = acc[mi][nj][r];
    }
}

// ---------------------------------------------------------------------------
extern "C" void kernel_launch(void* const* d_in, const int* in_sizes, int n_in,
                              void* d_out, int out_size, void* d_ws,
                              size_t ws_size, hipStream_t stream) {
  (void)in_sizes; (void)n_in; (void)out_size; (void)ws_size;
  const float* x = (const float*)d_in[0];
  const float* run = (const float*)d_in[1];
  float* out = (float*)d_out;
  uint8_t* ws = (uint8_t*)d_ws;

  float* C = (float*)ws;                              // 1 MB
  unsigned* sMax = (unsigned*)(ws + (1u << 20));      // 4 B (256 B slot)
  float* M = (float*)(ws + (1u << 20) + 256);         // 1 MB
  float* Ya = M + 262144;
  float* Yb = Ya + 262144;
  float* Za = Yb + 262144;
  float* Zb = Za + 262144;
  float* T = Zb + 262144;
  short* panels = (short*)(T + 262144);               // 512 KB

  (void)hipMemsetAsync(C, 0, (1u << 20) + 256, stream);  // zero C and sMax

  covar_k<<<dim3(10, CK_CHUNKS), 256, 0, stream>>>(x, C);
  prep_k<<<512, 256, 0, stream>>>(C, run, M, sMax);
  inityz_k<<<1024, 256, 0, stream>>>(M, sMax, Ya, Za);

  float *Y = Ya, *Yn = Yb, *Z = Za, *Zn = Zb;
  for (int it = 0; it < NS_ITERS; ++it) {
    mmT_k<<<dim3(16, 16), 256, 0, stream>>>(Z, Y, T);
    mmpair_k<<<dim3(16, 16, 2), 256, 0, stream>>>(Y, Z, T, Yn, Zn);
    float* tmp = Y; Y = Yn; Yn = tmp;
    tmp = Z; Z = Zn; Zn = tmp;
  }

  panel_k<<<1024, 256, 0, stream>>>(Z, sMax, panels);
  gemm_k<<<dim3(4, 2048), 256, 0, stream>>>(x, panels, out);
}

// Round 2
// 842.176 us; speedup vs baseline: 1.1094x; 1.1094x over previous
//
#include <hip/hip_runtime.h>
#include <stdint.h>

// ---------------------------------------------------------------------------
// BatchWhiten: out = x @ inv_sqrtm(max(0.1*running + 0.9*(x^T x)/N, 1e-5))
// x: [262144, 512] fp32, running: [512,512] fp32, out: [262144,512] fp32
// ---------------------------------------------------------------------------

#define N_ROWS 262144
#define D 512
#define NS_ITERS 5
#define CK_CHUNKS 64
#define CK_ROWS (N_ROWS / CK_CHUNKS)  // 4096
#define CK_STEPS (CK_ROWS / 32)       // 128

typedef float f32x4 __attribute__((ext_vector_type(4)));
typedef short s16x8 __attribute__((ext_vector_type(8)));
typedef short s16x4 __attribute__((ext_vector_type(4)));
typedef __bf16 bf16x8 __attribute__((ext_vector_type(8)));

static __device__ __forceinline__ unsigned short f2bf(float f) {
  unsigned u = __float_as_uint(f);
  u += 0x7FFFu + ((u >> 16) & 1u);  // RNE
  return (unsigned short)(u >> 16);
}

static __device__ __forceinline__ f32x4 mfma16(s16x8 a, s16x8 b, f32x4 c) {
  return __builtin_amdgcn_mfma_f32_16x16x32_bf16(
      __builtin_bit_cast(bf16x8, a), __builtin_bit_cast(bf16x8, b), c, 0, 0, 0);
}

#define SWZ4(c) (((c) ^ ((c) >> 2)) & 3)
#define SWZ8(c) (((c) ^ ((c) >> 3)) & 7)

// ---------------------------------------------------------------------------
// Kernel 1: C += x^T x, split-K, bf16 MFMA, upper tiles (mb<=nb) only.
// grid 640 (10 tiles x 64 chunks), block 256, XCD-swizzled so each chunk's
// 10 tile-blocks land on ONE XCD (share its L2 for the 8MB k-slab).
// ---------------------------------------------------------------------------
__global__ __launch_bounds__(256) void covar_k(const float* __restrict__ x,
                                               float* __restrict__ C) {
  __shared__ short ldsA[128 * 32];
  __shared__ short ldsB[128 * 32];

  // bijective XCD swizzle: 640 works = 8 XCDs x 80; a chunk's 10 works are
  // hw-stride-8 (co-dispatched) on the same XCD.
  const int hw = blockIdx.x;
  const int work = (hw & 7) * 80 + (hw >> 3);
  int t = work % 10, mb = 0, rl = 4;
  while (t >= rl) { t -= rl; ++mb; --rl; }
  const int nb = mb + t;
  const int chunk = work / 10;

  const int tid = threadIdx.x;
  const int c2 = (tid & 63) * 2;  // 0,2,..,126
  const int kh = tid >> 6;        // 0..3 (k-chunk of 8)

  const int lane = tid & 63;
  const int wave = tid >> 6;
  const int wr = wave >> 1, wc = wave & 1;
  const int l15 = lane & 15, g = lane >> 4;

  f32x4 acc[4][4];
#pragma unroll
  for (int i = 0; i < 4; ++i)
#pragma unroll
    for (int j = 0; j < 4; ++j) acc[i][j] = f32x4{0.f, 0.f, 0.f, 0.f};

  const size_t kbase0 = (size_t)chunk * CK_ROWS;

  for (int st = 0; st < CK_STEPS; ++st) {
    const size_t k0 = kbase0 + (size_t)st * 32;
    __syncthreads();
    {  // stage M-block
      const float* src = x + (k0 + kh * 8) * D + mb * 128 + c2;
      s16x8 p0, p1;
#pragma unroll
      for (int q = 0; q < 8; ++q) {
        float2 v = *(const float2*)(src + (size_t)q * D);
        p0[q] = (short)f2bf(v.x);
        p1[q] = (short)f2bf(v.y);
      }
      *(s16x8*)(ldsA + c2 * 32 + ((kh ^ SWZ4(c2)) << 3)) = p0;
      *(s16x8*)(ldsA + (c2 + 1) * 32 + ((kh ^ SWZ4(c2 + 1)) << 3)) = p1;
    }
    if (nb != mb) {  // stage N-block
      const float* src = x + (k0 + kh * 8) * D + nb * 128 + c2;
      s16x8 p0, p1;
#pragma unroll
      for (int q = 0; q < 8; ++q) {
        float2 v = *(const float2*)(src + (size_t)q * D);
        p0[q] = (short)f2bf(v.x);
        p1[q] = (short)f2bf(v.y);
      }
      *(s16x8*)(ldsB + c2 * 32 + ((kh ^ SWZ4(c2)) << 3)) = p0;
      *(s16x8*)(ldsB + (c2 + 1) * 32 + ((kh ^ SWZ4(c2 + 1)) << 3)) = p1;
    }
    __syncthreads();

    const short* Bp = (nb != mb) ? ldsB : ldsA;
    s16x8 af[4], bfv[4];
#pragma unroll
    for (int mi = 0; mi < 4; ++mi) {
      int m = 64 * wr + 16 * mi + l15;
      af[mi] = *(const s16x8*)(ldsA + m * 32 + ((g ^ SWZ4(m)) << 3));
    }
#pragma unroll
    for (int nj = 0; nj < 4; ++nj) {
      int n = 64 * wc + 16 * nj + l15;
      bfv[nj] = *(const s16x8*)(Bp + n * 32 + ((g ^ SWZ4(n)) << 3));
    }
#pragma unroll
    for (int mi = 0; mi < 4; ++mi)
#pragma unroll
      for (int nj = 0; nj < 4; ++nj)
        acc[mi][nj] = mfma16(af[mi], bfv[nj], acc[mi][nj]);
  }

  // epilogue: atomic accumulate into upper tile (mb,nb)
#pragma unroll
  for (int mi = 0; mi < 4; ++mi)
#pragma unroll
    for (int nj = 0; nj < 4; ++nj) {
      const int n = nb * 128 + 64 * wc + 16 * nj + l15;
#pragma unroll
      for (int r = 0; r < 4; ++r) {
        const int m = mb * 128 + 64 * wr + 16 * mi + 4 * g + r;
        atomicAdd(&C[(size_t)m * D + n], acc[mi][nj][r]);
      }
    }
}

// ---------------------------------------------------------------------------
// Kernel 2: M = max(0.1*running + (0.9/N)*C_sym, 1e-5); sMax = max row sum.
// ---------------------------------------------------------------------------
__global__ __launch_bounds__(256) void prep_k(const float* __restrict__ C,
                                              const float* __restrict__ run,
                                              float* __restrict__ M,
                                              unsigned* __restrict__ sMax) {
  const int r = blockIdx.x;
  const int t = threadIdx.x;
  const float cs = 0.9f / (float)N_ROWS;
  float sum = 0.f;
  for (int c = t; c < D; c += 256) {
    const int rr = r < c ? r : c;
    const int cc = r < c ? c : r;
    float v = 0.1f * run[(size_t)r * D + c] + cs * C[(size_t)rr * D + cc];
    v = fmaxf(v, 1e-5f);
    M[(size_t)r * D + c] = v;
    sum += v;  // all entries positive after clamp
  }
  __shared__ float red[256];
  red[t] = sum;
  __syncthreads();
  for (int off = 128; off > 0; off >>= 1) {
    if (t < off) red[t] += red[t + off];
    __syncthreads();
  }
  if (t == 0) atomicMax(sMax, __float_as_uint(red[0]));
}

// ---------------------------------------------------------------------------
// Kernel 3: Y = M/s ; Z = I.
// ---------------------------------------------------------------------------
__global__ __launch_bounds__(256) void inityz_k(const float* __restrict__ M,
                                                const unsigned* __restrict__ sMax,
                                                float* __restrict__ Y,
                                                float* __restrict__ Z) {
  const float inv = 1.0f / __uint_as_float(*sMax);
  const int i = blockIdx.x * 256 + threadIdx.x;
  Y[i] = M[i] * inv;
  Z[i] = ((i >> 9) == (i & 511)) ? 1.0f : 0.0f;
}

// ---------------------------------------------------------------------------
// 512x512x512 fp32 matmul body (32x32 tile / block, 2x2 per thread)
// ---------------------------------------------------------------------------
__device__ __forceinline__ void mm512_body(const float* __restrict__ A,
                                           const float* __restrict__ B,
                                           float* a00, float* a01, float* a10,
                                           float* a11, int rbase, int cbase) {
  __shared__ float As[32][36];
  __shared__ float Bs[32][36];
  const int t = threadIdx.x;
  const int tx = t & 15, ty = t >> 4;
  const int sr = t >> 3, sc = (t & 7) * 4;
  float c00 = 0.f, c01 = 0.f, c10 = 0.f, c11 = 0.f;
  for (int k0 = 0; k0 < D; k0 += 32) {
    __syncthreads();
    *(float4*)&As[sr][sc] = *(const float4*)(A + (size_t)(rbase + sr) * D + k0 + sc);
    *(float4*)&Bs[sr][sc] = *(const float4*)(B + (size_t)(k0 + sr) * D + cbase + sc);
    __syncthreads();
#pragma unroll
    for (int kk = 0; kk < 32; ++kk) {
      const float av0 = As[2 * ty][kk], av1 = As[2 * ty + 1][kk];
      const float2 bv = *(const float2*)&Bs[kk][2 * tx];
      c00 = fmaf(av0, bv.x, c00);
      c01 = fmaf(av0, bv.y, c01);
      c10 = fmaf(av1, bv.x, c10);
      c11 = fmaf(av1, bv.y, c11);
    }
  }
  *a00 = c00; *a01 = c01; *a10 = c10; *a11 = c11;
}

// T = 1.5 I - 0.5 * (Z @ Y)
__global__ __launch_bounds__(256) void mmT_k(const float* __restrict__ Zm,
                                             const float* __restrict__ Ym,
                                             float* __restrict__ T) {
  const int rbase = blockIdx.y * 32, cbase = blockIdx.x * 32;
  float a00, a01, a10, a11;
  mm512_body(Zm, Ym, &a00, &a01, &a10, &a11, rbase, cbase);
  const int tx = threadIdx.x & 15, ty = threadIdx.x >> 4;
  const int r0 = rbase + 2 * ty, c0 = cbase + 2 * tx;
  T[(size_t)r0 * D + c0] = (r0 == c0 ? 1.5f : 0.f) - 0.5f * a00;
  T[(size_t)r0 * D + c0 + 1] = (r0 == c0 + 1 ? 1.5f : 0.f) - 0.5f * a01;
  T[(size_t)(r0 + 1) * D + c0] = (r0 + 1 == c0 ? 1.5f : 0.f) - 0.5f * a10;
  T[(size_t)(r0 + 1) * D + c0 + 1] = (r0 + 1 == c0 + 1 ? 1.5f : 0.f) - 0.5f * a11;
}

// z=0: Ynew = Y @ T ; z=1: Znew = T @ Z
__global__ __launch_bounds__(256) void mmpair_k(const float* __restrict__ Y,
                                                const float* __restrict__ Z,
                                                const float* __restrict__ T,
                                                float* __restrict__ Yn,
                                                float* __restrict__ Zn) {
  const float* A = blockIdx.z ? T : Y;
  const float* B = blockIdx.z ? Z : T;
  float* O = blockIdx.z ? Zn : Yn;
  const int rbase = blockIdx.y * 32, cbase = blockIdx.x * 32;
  float a00, a01, a10, a11;
  mm512_body(A, B, &a00, &a01, &a10, &a11, rbase, cbase);
  const int tx = threadIdx.x & 15, ty = threadIdx.x >> 4;
  const int r0 = rbase + 2 * ty, c0 = cbase + 2 * tx;
  O[(size_t)r0 * D + c0] = a00;
  O[(size_t)r0 * D + c0 + 1] = a01;
  O[(size_t)(r0 + 1) * D + c0] = a10;
  O[(size_t)(r0 + 1) * D + c0 + 1] = a11;
}

// ---------------------------------------------------------------------------
// Kernel 4: build pre-swizzled bf16 B-panels: B = Z / sqrt(s).
// panel layout: [nb(4)][ks(8)][nl(128)][ch'(8)][e(8)] bf16  (512 KB)
// ---------------------------------------------------------------------------
__global__ __launch_bounds__(256) void panel_k(const float* __restrict__ Z,
                                               const unsigned* __restrict__ sMax,
                                               short* __restrict__ panels) {
  const float rs = rsqrtf(__uint_as_float(*sMax));
  const int i = blockIdx.x * 256 + threadIdx.x;  // 0..262143
  const int k = i >> 9, n = i & 511;
  const float v = Z[(size_t)k * D + n] * rs;
  const int nb = n >> 7, nl = n & 127;
  const int ks = k >> 6, kl = k & 63;
  const int ch = (kl >> 3) ^ SWZ8(nl), e = kl & 7;
  const size_t pi = (size_t)(((nb * 8 + ks) * 128 + nl)) * 64 + ch * 8 + e;
  panels[pi] = (short)f2bf(v);
}

// ---------------------------------------------------------------------------
// Kernel 5: out = x @ B.  grid 2048, block 256. Each block: 128 rows x ALL
// 512 cols (ct loop inside -> x panel fetched from HBM once, re-read from
// the block's own XCD L2 for ct=1..3). 128x128 tile per ct, BK=64.
// ---------------------------------------------------------------------------
__global__ __launch_bounds__(256) void gemm_k(const float* __restrict__ x,
                                              const short* __restrict__ panels,
                                              float* __restrict__ out) {
  __shared__ short ldsA[128 * 64];
  __shared__ short ldsB[128 * 64];
  const size_t rbase = (size_t)blockIdx.x * 128;
  const int tid = threadIdx.x;
  const int lane = tid & 63, wave = tid >> 6;
  const int wr = wave >> 1, wc = wave & 1;
  const int l15 = lane & 15, g = lane >> 4;

  const int mb8 = tid >> 4;         // 0..15
  const int koff = (tid & 15) * 4;  // 0..60
  const int chA = koff >> 3, subA = koff & 7;

  for (int ct = 0; ct < 4; ++ct) {
    f32x4 acc[4][4];
#pragma unroll
    for (int i = 0; i < 4; ++i)
#pragma unroll
      for (int j = 0; j < 4; ++j) acc[i][j] = f32x4{0.f, 0.f, 0.f, 0.f};

    for (int ks = 0; ks < 8; ++ks) {
      __syncthreads();
      // stage A: x[rbase..rbase+127][ks*64..+63] -> bf16 LDS
#pragma unroll
      for (int i = 0; i < 8; ++i) {
        const int m = mb8 + (i << 4);
        const float4 v = *(const float4*)(x + (rbase + m) * D + ks * 64 + koff);
        s16x4 p;
        p[0] = (short)f2bf(v.x);
        p[1] = (short)f2bf(v.y);
        p[2] = (short)f2bf(v.z);
        p[3] = (short)f2bf(v.w);
        *(s16x4*)(ldsA + m * 64 + ((chA ^ SWZ8(m)) << 3) + subA) = p;
      }
      // stage B: linear copy of pre-swizzled panel slice (16 KB)
      {
        const short* src = panels + ((size_t)(ct * 8 + ks) << 13) + tid * 8;
#pragma unroll
        for (int i = 0; i < 4; ++i)
          *(uint4*)(ldsB + i * 2048 + tid * 8) = *(const uint4*)(src + i * 2048);
      }
      __syncthreads();

#pragma unroll
      for (int kk = 0; kk < 2; ++kk) {
        s16x8 af[4], bfv[4];
#pragma unroll
        for (int mi = 0; mi < 4; ++mi) {
          const int m = 64 * wr + 16 * mi + l15;
          af[mi] = *(const s16x8*)(ldsA + m * 64 + ((((kk << 2) | g) ^ SWZ8(m)) << 3));
        }
#pragma unroll
        for (int nj = 0; nj < 4; ++nj) {
          const int n = 64 * wc + 16 * nj + l15;
          bfv[nj] = *(const s16x8*)(ldsB + n * 64 + ((((kk << 2) | g) ^ SWZ8(n)) << 3));
        }
#pragma unroll
        for (int mi = 0; mi < 4; ++mi)
#pragma unroll
          for (int nj = 0; nj < 4; ++nj)
            acc[mi][nj] = mfma16(af[mi], bfv[nj], acc[mi][nj]);
      }
    }

    // epilogue for this ct
#pragma unroll
    for (int mi = 0; mi < 4; ++mi)
#pragma unroll
      for (int nj = 0; nj < 4; ++nj) {
        const size_t row0 = rbase + 64 * wr + 16 * mi + 4 * g;
        const int col = ct * 128 + 64 * wc + 16 * nj + l15;
#pragma unroll
        for (int r = 0; r < 4; ++r)
          out[(row0 + r) * D + col] = acc[mi][nj][r];
      }
  }
}

// ---------------------------------------------------------------------------
extern "C" void kernel_launch(void* const* d_in, const int* in_sizes, int n_in,
                              void* d_out, int out_size, void* d_ws,
                              size_t ws_size, hipStream_t stream) {
  (void)in_sizes; (void)n_in; (void)out_size; (void)ws_size;
  const float* x = (const float*)d_in[0];
  const float* run = (const float*)d_in[1];
  float* out = (float*)d_out;
  uint8_t* ws = (uint8_t*)d_ws;

  float* C = (float*)ws;                              // 1 MB
  unsigned* sMax = (unsigned*)(ws + (1u << 20));      // 4 B (256 B slot)
  float* M = (float*)(ws + (1u << 20) + 256);         // 1 MB
  float* Ya = M + 262144;
  float* Yb = Ya + 262144;
  float* Za = Yb + 262144;
  float* Zb = Za + 262144;
  float* T = Zb + 262144;
  short* panels = (short*)(T + 262144);               // 512 KB

  (void)hipMemsetAsync(C, 0, (1u << 20) + 256, stream);  // zero C and sMax

  covar_k<<<640, 256, 0, stream>>>(x, C);
  prep_k<<<512, 256, 0, stream>>>(C, run, M, sMax);
  inityz_k<<<1024, 256, 0, stream>>>(M, sMax, Ya, Za);

  float *Y = Ya, *Yn = Yb, *Z = Za, *Zn = Zb;
  for (int it = 0; it < NS_ITERS; ++it) {
    mmT_k<<<dim3(16, 16), 256, 0, stream>>>(Z, Y, T);
    mmpair_k<<<dim3(16, 16, 2), 256, 0, stream>>>(Y, Z, T, Yn, Zn);
    float* tmp = Y; Y = Yn; Yn = tmp;
    tmp = Z; Z = Zn; Zn = tmp;
  }

  panel_k<<<1024, 256, 0, stream>>>(Z, sMax, panels);
  gemm_k<<<2048, 256, 0, stream>>>(x, panels, out);
}

// Round 3
// 819.205 us; speedup vs baseline: 1.1405x; 1.0280x over previous
//
#include <hip/hip_runtime.h>
#include <stdint.h>

// ---------------------------------------------------------------------------
// BatchWhiten: out = x @ inv_sqrtm(max(0.1*running + 0.9*(x^T x)/N, 1e-5))
// x: [262144, 512] fp32, running: [512,512] fp32, out: [262144,512] fp32
// ---------------------------------------------------------------------------

#define N_ROWS 262144
#define D 512
#define NS_ITERS 5
#define CK_CHUNKS 64
#define CK_ROWS (N_ROWS / CK_CHUNKS)  // 4096
#define CK_STEPS (CK_ROWS / 32)       // 128

typedef float f32x4 __attribute__((ext_vector_type(4)));
typedef short s16x8 __attribute__((ext_vector_type(8)));
typedef short s16x4 __attribute__((ext_vector_type(4)));
typedef __bf16 bf16x8 __attribute__((ext_vector_type(8)));

static __device__ __forceinline__ unsigned short f2bf(float f) {
  unsigned u = __float_as_uint(f);
  u += 0x7FFFu + ((u >> 16) & 1u);  // RNE
  return (unsigned short)(u >> 16);
}

static __device__ __forceinline__ f32x4 mfma16(s16x8 a, s16x8 b, f32x4 c) {
  return __builtin_amdgcn_mfma_f32_16x16x32_bf16(
      __builtin_bit_cast(bf16x8, a), __builtin_bit_cast(bf16x8, b), c, 0, 0, 0);
}

#define SWZ4(c) (((c) ^ ((c) >> 2)) & 3)
#define SWZ8(c) (((c) ^ ((c) >> 3)) & 7)

// ---------------------------------------------------------------------------
// Kernel 1: C += x^T x, split-K, bf16 MFMA, upper tiles (mb<=nb) only.
// grid 640 (10 tiles x 64 chunks), block 256, XCD-swizzled so each chunk's
// 10 tile-blocks land on ONE XCD (share its L2 for the 8MB k-slab).
// ---------------------------------------------------------------------------
__global__ __launch_bounds__(256) void covar_k(const float* __restrict__ x,
                                               float* __restrict__ C) {
  __shared__ short ldsA[128 * 32];
  __shared__ short ldsB[128 * 32];

  // bijective XCD swizzle: 640 works = 8 XCDs x 80; a chunk's 10 works are
  // hw-stride-8 (co-dispatched) on the same XCD.
  const int hw = blockIdx.x;
  const int work = (hw & 7) * 80 + (hw >> 3);
  int t = work % 10, mb = 0, rl = 4;
  while (t >= rl) { t -= rl; ++mb; --rl; }
  const int nb = mb + t;
  const int chunk = work / 10;

  const int tid = threadIdx.x;
  const int c2 = (tid & 63) * 2;  // 0,2,..,126
  const int kh = tid >> 6;        // 0..3 (k-chunk of 8)

  const int lane = tid & 63;
  const int wave = tid >> 6;
  const int wr = wave >> 1, wc = wave & 1;
  const int l15 = lane & 15, g = lane >> 4;

  f32x4 acc[4][4];
#pragma unroll
  for (int i = 0; i < 4; ++i)
#pragma unroll
    for (int j = 0; j < 4; ++j) acc[i][j] = f32x4{0.f, 0.f, 0.f, 0.f};

  const size_t kbase0 = (size_t)chunk * CK_ROWS;

  for (int st = 0; st < CK_STEPS; ++st) {
    const size_t k0 = kbase0 + (size_t)st * 32;
    __syncthreads();
    {  // stage M-block
      const float* src = x + (k0 + kh * 8) * D + mb * 128 + c2;
      s16x8 p0, p1;
#pragma unroll
      for (int q = 0; q < 8; ++q) {
        float2 v = *(const float2*)(src + (size_t)q * D);
        p0[q] = (short)f2bf(v.x);
        p1[q] = (short)f2bf(v.y);
      }
      *(s16x8*)(ldsA + c2 * 32 + ((kh ^ SWZ4(c2)) << 3)) = p0;
      *(s16x8*)(ldsA + (c2 + 1) * 32 + ((kh ^ SWZ4(c2 + 1)) << 3)) = p1;
    }
    if (nb != mb) {  // stage N-block
      const float* src = x + (k0 + kh * 8) * D + nb * 128 + c2;
      s16x8 p0, p1;
#pragma unroll
      for (int q = 0; q < 8; ++q) {
        float2 v = *(const float2*)(src + (size_t)q * D);
        p0[q] = (short)f2bf(v.x);
        p1[q] = (short)f2bf(v.y);
      }
      *(s16x8*)(ldsB + c2 * 32 + ((kh ^ SWZ4(c2)) << 3)) = p0;
      *(s16x8*)(ldsB + (c2 + 1) * 32 + ((kh ^ SWZ4(c2 + 1)) << 3)) = p1;
    }
    __syncthreads();

    const short* Bp = (nb != mb) ? ldsB : ldsA;
    s16x8 af[4], bfv[4];
#pragma unroll
    for (int mi = 0; mi < 4; ++mi) {
      int m = 64 * wr + 16 * mi + l15;
      af[mi] = *(const s16x8*)(ldsA + m * 32 + ((g ^ SWZ4(m)) << 3));
    }
#pragma unroll
    for (int nj = 0; nj < 4; ++nj) {
      int n = 64 * wc + 16 * nj + l15;
      bfv[nj] = *(const s16x8*)(Bp + n * 32 + ((g ^ SWZ4(n)) << 3));
    }
#pragma unroll
    for (int mi = 0; mi < 4; ++mi)
#pragma unroll
      for (int nj = 0; nj < 4; ++nj)
        acc[mi][nj] = mfma16(af[mi], bfv[nj], acc[mi][nj]);
  }

  // epilogue: atomic accumulate into upper tile (mb,nb)
#pragma unroll
  for (int mi = 0; mi < 4; ++mi)
#pragma unroll
    for (int nj = 0; nj < 4; ++nj) {
      const int n = nb * 128 + 64 * wc + 16 * nj + l15;
#pragma unroll
      for (int r = 0; r < 4; ++r) {
        const int m = mb * 128 + 64 * wr + 16 * mi + 4 * g + r;
        atomicAdd(&C[(size_t)m * D + n], acc[mi][nj][r]);
      }
    }
}

// ---------------------------------------------------------------------------
// Kernel 2: M = max(0.1*running + (0.9/N)*C_sym, 1e-5); sMax = max row sum.
// ---------------------------------------------------------------------------
__global__ __launch_bounds__(256) void prep_k(const float* __restrict__ C,
                                              const float* __restrict__ run,
                                              float* __restrict__ M,
                                              unsigned* __restrict__ sMax) {
  const int r = blockIdx.x;
  const int t = threadIdx.x;
  const float cs = 0.9f / (float)N_ROWS;
  float sum = 0.f;
  for (int c = t; c < D; c += 256) {
    const int rr = r < c ? r : c;
    const int cc = r < c ? c : r;
    float v = 0.1f * run[(size_t)r * D + c] + cs * C[(size_t)rr * D + cc];
    v = fmaxf(v, 1e-5f);
    M[(size_t)r * D + c] = v;
    sum += v;  // all entries positive after clamp
  }
  __shared__ float red[256];
  red[t] = sum;
  __syncthreads();
  for (int off = 128; off > 0; off >>= 1) {
    if (t < off) red[t] += red[t + off];
    __syncthreads();
  }
  if (t == 0) atomicMax(sMax, __float_as_uint(red[0]));
}

// ---------------------------------------------------------------------------
// Kernel 3: Y = M/s ; Z = I.
// ---------------------------------------------------------------------------
__global__ __launch_bounds__(256) void inityz_k(const float* __restrict__ M,
                                                const unsigned* __restrict__ sMax,
                                                float* __restrict__ Y,
                                                float* __restrict__ Z) {
  const float inv = 1.0f / __uint_as_float(*sMax);
  const int i = blockIdx.x * 256 + threadIdx.x;
  Y[i] = M[i] * inv;
  Z[i] = ((i >> 9) == (i & 511)) ? 1.0f : 0.0f;
}

// ---------------------------------------------------------------------------
// 512x512x512 fp32 matmul body (32x32 tile / block, 2x2 per thread)
// ---------------------------------------------------------------------------
__device__ __forceinline__ void mm512_body(const float* __restrict__ A,
                                           const float* __restrict__ B,
                                           float* a00, float* a01, float* a10,
                                           float* a11, int rbase, int cbase) {
  __shared__ float As[32][36];
  __shared__ float Bs[32][36];
  const int t = threadIdx.x;
  const int tx = t & 15, ty = t >> 4;
  const int sr = t >> 3, sc = (t & 7) * 4;
  float c00 = 0.f, c01 = 0.f, c10 = 0.f, c11 = 0.f;
  for (int k0 = 0; k0 < D; k0 += 32) {
    __syncthreads();
    *(float4*)&As[sr][sc] = *(const float4*)(A + (size_t)(rbase + sr) * D + k0 + sc);
    *(float4*)&Bs[sr][sc] = *(const float4*)(B + (size_t)(k0 + sr) * D + cbase + sc);
    __syncthreads();
#pragma unroll
    for (int kk = 0; kk < 32; ++kk) {
      const float av0 = As[2 * ty][kk], av1 = As[2 * ty + 1][kk];
      const float2 bv = *(const float2*)&Bs[kk][2 * tx];
      c00 = fmaf(av0, bv.x, c00);
      c01 = fmaf(av0, bv.y, c01);
      c10 = fmaf(av1, bv.x, c10);
      c11 = fmaf(av1, bv.y, c11);
    }
  }
  *a00 = c00; *a01 = c01; *a10 = c10; *a11 = c11;
}

// T = 1.5 I - 0.5 * (Z @ Y)
__global__ __launch_bounds__(256) void mmT_k(const float* __restrict__ Zm,
                                             const float* __restrict__ Ym,
                                             float* __restrict__ T) {
  const int rbase = blockIdx.y * 32, cbase = blockIdx.x * 32;
  float a00, a01, a10, a11;
  mm512_body(Zm, Ym, &a00, &a01, &a10, &a11, rbase, cbase);
  const int tx = threadIdx.x & 15, ty = threadIdx.x >> 4;
  const int r0 = rbase + 2 * ty, c0 = cbase + 2 * tx;
  T[(size_t)r0 * D + c0] = (r0 == c0 ? 1.5f : 0.f) - 0.5f * a00;
  T[(size_t)r0 * D + c0 + 1] = (r0 == c0 + 1 ? 1.5f : 0.f) - 0.5f * a01;
  T[(size_t)(r0 + 1) * D + c0] = (r0 + 1 == c0 ? 1.5f : 0.f) - 0.5f * a10;
  T[(size_t)(r0 + 1) * D + c0 + 1] = (r0 + 1 == c0 + 1 ? 1.5f : 0.f) - 0.5f * a11;
}

// z=0: Ynew = Y @ T ; z=1: Znew = T @ Z
__global__ __launch_bounds__(256) void mmpair_k(const float* __restrict__ Y,
                                                const float* __restrict__ Z,
                                                const float* __restrict__ T,
                                                float* __restrict__ Yn,
                                                float* __restrict__ Zn) {
  const float* A = blockIdx.z ? T : Y;
  const float* B = blockIdx.z ? Z : T;
  float* O = blockIdx.z ? Zn : Yn;
  const int rbase = blockIdx.y * 32, cbase = blockIdx.x * 32;
  float a00, a01, a10, a11;
  mm512_body(A, B, &a00, &a01, &a10, &a11, rbase, cbase);
  const int tx = threadIdx.x & 15, ty = threadIdx.x >> 4;
  const int r0 = rbase + 2 * ty, c0 = cbase + 2 * tx;
  O[(size_t)r0 * D + c0] = a00;
  O[(size_t)r0 * D + c0 + 1] = a01;
  O[(size_t)(r0 + 1) * D + c0] = a10;
  O[(size_t)(r0 + 1) * D + c0 + 1] = a11;
}

// ---------------------------------------------------------------------------
// Kernel 4: build pre-swizzled bf16 B-panels: B = Z / sqrt(s).
// panel layout: [nb(4)][ks(8)][nl(128)][ch'(8)][e(8)] bf16  (512 KB)
// ---------------------------------------------------------------------------
__global__ __launch_bounds__(256) void panel_k(const float* __restrict__ Z,
                                               const unsigned* __restrict__ sMax,
                                               short* __restrict__ panels) {
  const float rs = rsqrtf(__uint_as_float(*sMax));
  const int i = blockIdx.x * 256 + threadIdx.x;  // 0..262143
  const int k = i >> 9, n = i & 511;
  const float v = Z[(size_t)k * D + n] * rs;
  const int nb = n >> 7, nl = n & 127;
  const int ks = k >> 6, kl = k & 63;
  const int ch = (kl >> 3) ^ SWZ8(nl), e = kl & 7;
  const size_t pi = (size_t)(((nb * 8 + ks) * 128 + nl)) * 64 + ch * 8 + e;
  panels[pi] = (short)f2bf(v);
}

// ---------------------------------------------------------------------------
// Kernel 5: out = x @ B.  grid 8192, block 256. Work (rp, ct): 128-row panel
// rp, 128-col tile ct. XCD swizzle puts the 4 ct-sharers of a panel on the
// SAME XCD at hw stride 8 (co-dispatched, near-lockstep) so panel slices are
// fetched from HBM once and hit that XCD's L2 for the other 3. Epilogue uses
// nontemporal stores so the 512MB out stream doesn't evict shared panels.
// ---------------------------------------------------------------------------
__global__ __launch_bounds__(256) void gemm_k(const float* __restrict__ x,
                                              const short* __restrict__ panels,
                                              float* __restrict__ out) {
  __shared__ short ldsA[128 * 64];
  __shared__ short ldsB[128 * 64];

  // bijective XCD swizzle (8192 = 8 XCDs x 1024 works)
  const int hw = blockIdx.x;
  const int q = hw & 7, j = hw >> 3;
  const int ct = j & 3;
  const int rp = ((j >> 2) << 3) | q;
  const size_t rbase = (size_t)rp * 128;

  const int tid = threadIdx.x;
  const int lane = tid & 63, wave = tid >> 6;
  const int wr = wave >> 1, wc = wave & 1;
  const int l15 = lane & 15, g = lane >> 4;

  const int mb8 = tid >> 4;         // 0..15
  const int koff = (tid & 15) * 4;  // 0..60
  const int chA = koff >> 3, subA = koff & 7;

  f32x4 acc[4][4];
#pragma unroll
  for (int i = 0; i < 4; ++i)
#pragma unroll
    for (int j2 = 0; j2 < 4; ++j2) acc[i][j2] = f32x4{0.f, 0.f, 0.f, 0.f};

  for (int ks = 0; ks < 8; ++ks) {
    __syncthreads();
    // stage A: x[rbase..rbase+127][ks*64..+63] -> bf16 LDS
#pragma unroll
    for (int i = 0; i < 8; ++i) {
      const int m = mb8 + (i << 4);
      const float4 v = *(const float4*)(x + (rbase + m) * D + ks * 64 + koff);
      s16x4 p;
      p[0] = (short)f2bf(v.x);
      p[1] = (short)f2bf(v.y);
      p[2] = (short)f2bf(v.z);
      p[3] = (short)f2bf(v.w);
      *(s16x4*)(ldsA + m * 64 + ((chA ^ SWZ8(m)) << 3) + subA) = p;
    }
    // stage B: linear copy of pre-swizzled panel slice (16 KB)
    {
      const short* src = panels + ((size_t)(ct * 8 + ks) << 13) + tid * 8;
#pragma unroll
      for (int i = 0; i < 4; ++i)
        *(uint4*)(ldsB + i * 2048 + tid * 8) = *(const uint4*)(src + i * 2048);
    }
    __syncthreads();

#pragma unroll
    for (int kk = 0; kk < 2; ++kk) {
      s16x8 af[4], bfv[4];
#pragma unroll
      for (int mi = 0; mi < 4; ++mi) {
        const int m = 64 * wr + 16 * mi + l15;
        af[mi] = *(const s16x8*)(ldsA + m * 64 + ((((kk << 2) | g) ^ SWZ8(m)) << 3));
      }
#pragma unroll
      for (int nj = 0; nj < 4; ++nj) {
        const int n = 64 * wc + 16 * nj + l15;
        bfv[nj] = *(const s16x8*)(ldsB + n * 64 + ((((kk << 2) | g) ^ SWZ8(n)) << 3));
      }
#pragma unroll
      for (int mi = 0; mi < 4; ++mi)
#pragma unroll
        for (int nj = 0; nj < 4; ++nj)
          acc[mi][nj] = mfma16(af[mi], bfv[nj], acc[mi][nj]);
    }
  }

  // epilogue: nontemporal stores (don't pollute L2 with the out stream)
#pragma unroll
  for (int mi = 0; mi < 4; ++mi)
#pragma unroll
    for (int nj = 0; nj < 4; ++nj) {
      const size_t row0 = rbase + 64 * wr + 16 * mi + 4 * g;
      const int col = ct * 128 + 64 * wc + 16 * nj + l15;
#pragma unroll
      for (int r = 0; r < 4; ++r)
        __builtin_nontemporal_store(acc[mi][nj][r], &out[(row0 + r) * D + col]);
    }
}

// ---------------------------------------------------------------------------
extern "C" void kernel_launch(void* const* d_in, const int* in_sizes, int n_in,
                              void* d_out, int out_size, void* d_ws,
                              size_t ws_size, hipStream_t stream) {
  (void)in_sizes; (void)n_in; (void)out_size; (void)ws_size;
  const float* x = (const float*)d_in[0];
  const float* run = (const float*)d_in[1];
  float* out = (float*)d_out;
  uint8_t* ws = (uint8_t*)d_ws;

  float* C = (float*)ws;                              // 1 MB
  unsigned* sMax = (unsigned*)(ws + (1u << 20));      // 4 B (256 B slot)
  float* M = (float*)(ws + (1u << 20) + 256);         // 1 MB
  float* Ya = M + 262144;
  float* Yb = Ya + 262144;
  float* Za = Yb + 262144;
  float* Zb = Za + 262144;
  float* T = Zb + 262144;
  short* panels = (short*)(T + 262144);               // 512 KB

  (void)hipMemsetAsync(C, 0, (1u << 20) + 256, stream);  // zero C and sMax

  covar_k<<<640, 256, 0, stream>>>(x, C);
  prep_k<<<512, 256, 0, stream>>>(C, run, M, sMax);
  inityz_k<<<1024, 256, 0, stream>>>(M, sMax, Ya, Za);

  float *Y = Ya, *Yn = Yb, *Z = Za, *Zn = Zb;
  for (int it = 0; it < NS_ITERS; ++it) {
    mmT_k<<<dim3(16, 16), 256, 0, stream>>>(Z, Y, T);
    mmpair_k<<<dim3(16, 16, 2), 256, 0, stream>>>(Y, Z, T, Yn, Zn);
    float* tmp = Y; Y = Yn; Yn = tmp;
    tmp = Z; Z = Zn; Zn = tmp;
  }

  panel_k<<<1024, 256, 0, stream>>>(Z, sMax, panels);
  gemm_k<<<8192, 256, 0, stream>>>(x, panels, out);
}